// Round 18
// baseline (157.086 us; speedup 1.0000x reference)
//
#include <hip/hip_runtime.h>

#define NEG_SLOPE 0.2f
#define CBSH 7            // 128 nodes per coarse bucket
#define MAXNC 512         // max buckets (N <= 65536)
#define BCAP 4096         // fixed per-bucket edge capacity (mean ~2046)

typedef __attribute__((ext_vector_type(8))) short short8;
typedef __attribute__((ext_vector_type(4))) float f32x4;

__device__ __forceinline__ unsigned short f2bf(float f) {
  unsigned u = __float_as_uint(f);
  unsigned r = (u + 0x7FFFu + ((u >> 16) & 1u)) >> 16;
  return (unsigned short)r;
}
__device__ __forceinline__ unsigned pack_bf16(float lo, float hi) {
  return (unsigned)f2bf(lo) | ((unsigned)f2bf(hi) << 16);
}
__device__ __forceinline__ float bflo(unsigned u) {
  return __uint_as_float(u << 16);
}
__device__ __forceinline__ float bfhi(unsigned u) {
  return __uint_as_float(u & 0xFFFF0000u);
}
__device__ __forceinline__ void gload_lds16(const void* g, void* l) {
  __builtin_amdgcn_global_load_lds(
      (const __attribute__((address_space(1))) unsigned*)g,
      (__attribute__((address_space(3))) unsigned*)l, 16, 0, 0);
}

// ---------------------------------------------------------------------------
// prep: all four W[K][128] fp32 -> Wt[128][K] bf16 transposes + gcur zeroing
// in ONE launch. Segment boundaries are multiples of 64 (wave-clean).
// ---------------------------------------------------------------------------
__device__ __forceinline__ void wconv_item(const float* __restrict__ W,
                                           unsigned* __restrict__ Wt, int K,
                                           int t) {
  int per = K >> 3;
  int col = t / per;
  int kc = (t - col * per) << 3;
  float w[8];
#pragma unroll
  for (int j = 0; j < 8; ++j) w[j] = W[(size_t)(kc + j) * 128 + col];
  uint4 o = make_uint4(pack_bf16(w[0], w[1]), pack_bf16(w[2], w[3]),
                       pack_bf16(w[4], w[5]), pack_bf16(w[6], w[7]));
  *(uint4*)&Wt[((size_t)col * K + kc) >> 1] = o;
}

__global__ __launch_bounds__(256) void prep(
    const float* __restrict__ W0, const float* __restrict__ Ws0,
    const float* __restrict__ W2c, const float* __restrict__ Ws2,
    unsigned* __restrict__ WtP0, unsigned* __restrict__ WtS0,
    unsigned* __restrict__ WtP2, unsigned* __restrict__ WtS2,
    int* __restrict__ gcur) {
  int t = blockIdx.x * 256 + threadIdx.x;
  if (t < 4096) wconv_item(W0, WtP0, 256, t);
  else if (t < 8192) wconv_item(Ws0, WtS0, 256, t - 4096);
  else if (t < 10240) wconv_item(W2c, WtP2, 128, t - 8192);
  else if (t < 12288) wconv_item(Ws2, WtS2, 128, t - 10240);
  else if (t < 12288 + MAXNC) gcur[t - 12288] = 0;
}

// ---------------------------------------------------------------------------
// cscatter body (512 threads): block-local counting sort of a 4096-edge
// chunk; per-bucket runs burst-written into cb*BCAP + reserved global run.
// ---------------------------------------------------------------------------
__device__ void cscatter_body(char* ldsraw, int chunk,
                              const int* __restrict__ src,
                              const int* __restrict__ trg,
                              int* __restrict__ gcur,
                              unsigned* __restrict__ EB, int E, int NC) {
  int* hist = (int*)ldsraw;
  int* gb = hist + MAXNC;
  int* lcur = gb + MAXNC;
  unsigned* lbuf = (unsigned*)(lcur + MAXNC);
  unsigned short* cb16 = (unsigned short*)(lbuf + 4096);
  int tid = threadIdx.x;
  int e0 = chunk * 4096;
  int cnt = E - e0;
  if (cnt > 4096) cnt = 4096;
  for (int i = tid; i < NC; i += 512) hist[i] = 0;
  __syncthreads();
  unsigned pk[8];
  unsigned short cbr[8];
  int mine = 0;
#pragma unroll
  for (int j = 0; j < 8; ++j) {
    int i = tid + j * 512;
    if (i < cnt) {
      int e = e0 + i;
      int s = src[e];
      int t = trg[e];
      int cb = t >> CBSH;
      pk[j] = ((unsigned)s << CBSH) | (unsigned)(t & ((1 << CBSH) - 1));
      cbr[j] = (unsigned short)cb;
      atomicAdd(&hist[cb], 1);
      mine = j + 1;
    }
  }
  __syncthreads();
  for (int i = tid; i < NC; i += 512)
    gb[i] = hist[i] ? (i * BCAP + atomicAdd(&gcur[i], hist[i])) : 0;
  __syncthreads();
  if (tid == 0) {
    int run = 0;
    for (int i = 0; i < NC; ++i) {
      int v = hist[i];
      hist[i] = run;
      run += v;
    }
  }
  __syncthreads();
  for (int i = tid; i < NC; i += 512) lcur[i] = hist[i];
  __syncthreads();
  for (int j = 0; j < mine; ++j) {
    int p = atomicAdd(&lcur[cbr[j]], 1);
    lbuf[p] = pk[j];
    cb16[p] = cbr[j];
  }
  __syncthreads();
  for (int i = tid; i < cnt; i += 512) {
    int cb = cb16[i];
    EB[gb[cb] + (i - hist[cb])] = lbuf[i];
  }
}

// One block per bucket: per-node degrees -> rowbeg/rowend, in-bucket scatter.
// Prefix scan parallelized (Hillis-Steele over 128 entries, 7 steps).
__global__ __launch_bounds__(256) void bfill(const unsigned* __restrict__ EB,
                                             const int* __restrict__ gcur,
                                             int* __restrict__ rowbeg,
                                             int* __restrict__ rowend,
                                             int* __restrict__ SS, int N) {
  __shared__ int deg[128], pfx[128], cur[128];
  int cb = blockIdx.x;
  int b0 = cb * BCAP;
  int b1 = b0 + gcur[cb];
  int n0 = cb << CBSH;
  int tid = threadIdx.x;
  if (tid < 128) deg[tid] = 0;
  __syncthreads();
  for (int i = b0 + tid; i < b1; i += 256)
    atomicAdd(&deg[EB[i] & ((1 << CBSH) - 1)], 1);
  __syncthreads();
  if (tid < 128) pfx[tid] = deg[tid];
  __syncthreads();
#pragma unroll
  for (int s = 1; s < 128; s <<= 1) {
    int v = 0;
    if (tid < 128 && tid >= s) v = pfx[tid - s];
    __syncthreads();
    if (tid < 128) pfx[tid] += v;
    __syncthreads();
  }
  // pfx[t] = inclusive prefix; exclusive offset = pfx[t] - deg[t]
  if (tid < 128) {
    int lo = b0 + pfx[tid] - deg[tid];
    cur[tid] = lo;
    int n = n0 + tid;
    if (n < N) {
      rowbeg[n] = lo;
      rowend[n] = lo + deg[tid];
    }
  }
  __syncthreads();
  for (int i = b0 + tid; i < b1; i += 256) {
    unsigned pk = EB[i];
    int pos = atomicAdd(&cur[pk & ((1 << CBSH) - 1)], 1);
    SS[pos] = (int)(pk >> CBSH);
  }
}

// ---------------------------------------------------------------------------
// gemm body — 128-row tile, 8 waves (512 thr), K_STEP=32 (verified passing).
// LDS: A-frags 8KB @0, BP @8192, BS @16384; epilogue Cs[64][132] aliases,
// two 64-row halves.
// ---------------------------------------------------------------------------
template <int KK, bool AF32>
__device__ void gemm_body(char* ldsraw, int row0, const void* __restrict__ Av,
                          const unsigned* __restrict__ BtP,
                          const unsigned* __restrict__ BtS,
                          unsigned* __restrict__ Cb,
                          unsigned* __restrict__ PH,
                          const float* __restrict__ a_src,
                          const float* __restrict__ a_trg,
                          float* __restrict__ ssrc, float* __restrict__ strg,
                          int M) {
  constexpr int NSTEP = KK / 32;
  float(*Cs)[132] = (float(*)[132])ldsraw;

  const int tid = threadIdx.x;
  const int lane = tid & 63;
  const int w = tid >> 6;  // 0..7

  f32x4 accP[8], accS[8];
#pragma unroll
  for (int c = 0; c < 8; ++c) {
    accP[c] = (f32x4)0.f;
    accS[c] = (f32x4)0.f;
  }

  const int arow = tid >> 2;
  const int akq = (tid & 3) << 3;
  const int agr = row0 + arow;
  const int abyte =
      ((((arow >> 4) << 6) | ((tid & 3) << 4) | (arow & 15)) << 4);
  const unsigned short* BP16 = (const unsigned short*)BtP;
  const unsigned short* BS16 = (const unsigned short*)BtS;
  const int bg = lane >> 4;
  const int br = lane & 15;

  for (int t = 0; t < NSTEP; ++t) {
    const int k0 = t << 5;
    {
      size_t eoff = (size_t)(16 * w + br) * KK + k0 + 8 * bg;
      gload_lds16(BP16 + eoff, ldsraw + 8192 + w * 1024);
      gload_lds16(BS16 + eoff, ldsraw + 16384 + w * 1024);
    }
    {
      uint4 p;
      if constexpr (AF32) {
        const float* A = (const float*)Av;
        float4 v0 = make_float4(0.f, 0.f, 0.f, 0.f), v1 = v0;
        if (agr < M) {
          v0 = *(const float4*)&A[(size_t)agr * KK + k0 + akq];
          v1 = *(const float4*)&A[(size_t)agr * KK + k0 + akq + 4];
        }
        p = make_uint4(pack_bf16(v0.x, v0.y), pack_bf16(v0.z, v0.w),
                       pack_bf16(v1.x, v1.y), pack_bf16(v1.z, v1.w));
      } else {
        const unsigned short* A = (const unsigned short*)Av;
        p = make_uint4(0u, 0u, 0u, 0u);
        if (agr < M) p = *(const uint4*)&A[(size_t)agr * KK + k0 + akq];
      }
      *(uint4*)(ldsraw + abyte) = p;
    }
    __syncthreads();
    short8 af = *(const short8*)(ldsraw + w * 1024 + lane * 16);
#pragma unroll
    for (int c = 0; c < 8; ++c) {
      short8 bp = *(const short8*)(ldsraw + 8192 + c * 1024 + lane * 16);
      accP[c] =
          __builtin_amdgcn_mfma_f32_16x16x32_bf16(af, bp, accP[c], 0, 0, 0);
      short8 bs = *(const short8*)(ldsraw + 16384 + c * 1024 + lane * 16);
      accS[c] =
          __builtin_amdgcn_mfma_f32_16x16x32_bf16(af, bs, accS[c], 0, 0, 0);
    }
    __syncthreads();
  }

  const int hrow = lane >> 5;
  const int c32 = lane & 31;
  const int wh = w >> 2;
  const int w4 = w & 3;

  // ---- proj epilogue (two 64-row halves): PH (bf16) + fused scores ----
#pragma unroll
  for (int h = 0; h < 2; ++h) {
    if (wh == h) {
#pragma unroll
      for (int c = 0; c < 8; ++c)
#pragma unroll
        for (int r = 0; r < 4; ++r)
          Cs[16 * w4 + ((lane >> 4) << 2) + r][16 * c + (lane & 15)] =
              accP[c][r];
    }
    __syncthreads();
    if (wh == h) {
#pragma unroll
      for (int i = 0; i < 8; ++i) {
        int lr = 16 * w4 + 2 * i + hrow;
        int gr = row0 + 64 * h + lr;
        if (gr < M) {
          float4 v = *(const float4*)&Cs[lr][c32 * 4];
          *(uint2*)&PH[(size_t)gr * 64 + c32 * 2] =
              make_uint2(pack_bf16(v.x, v.y), pack_bf16(v.z, v.w));
        }
      }
      int tid4 = tid - h * 256;
      int srow = tid4 >> 2;
      int q = tid4 & 3;
      int gr = row0 + 64 * h + srow;
      float ds = 0.f, dt = 0.f;
#pragma unroll
      for (int j = 0; j < 8; ++j) {
        int col = q * 32 + j * 4;
        float4 v = *(const float4*)&Cs[srow][col];
        float4 asv = *(const float4*)&a_src[col];
        float4 atv = *(const float4*)&a_trg[col];
        ds += v.x * asv.x + v.y * asv.y + v.z * asv.z + v.w * asv.w;
        dt += v.x * atv.x + v.y * atv.y + v.z * atv.z + v.w * atv.w;
      }
      ds += __shfl_xor(ds, 1, 64);
      dt += __shfl_xor(dt, 1, 64);
      if (gr < M && (q & 1) == 0) {
        int hh = q >> 1;
        ssrc[gr * 2 + hh] = ds;
        strg[gr * 2 + hh] = dt;
      }
    }
    __syncthreads();
  }

  // ---- skip epilogue (two halves): Cb (packed bf16) ----
#pragma unroll
  for (int h = 0; h < 2; ++h) {
    if (wh == h) {
#pragma unroll
      for (int c = 0; c < 8; ++c)
#pragma unroll
        for (int r = 0; r < 4; ++r)
          Cs[16 * w4 + ((lane >> 4) << 2) + r][16 * c + (lane & 15)] =
              accS[c][r];
    }
    __syncthreads();
    if (wh == h) {
#pragma unroll
      for (int i = 0; i < 8; ++i) {
        int lr = 16 * w4 + 2 * i + hrow;
        int gr = row0 + 64 * h + lr;
        if (gr < M) {
          float4 v = *(const float4*)&Cs[lr][c32 * 4];
          *(uint2*)&Cb[(size_t)gr * 64 + c32 * 2] =
              make_uint2(pack_bf16(v.x, v.y), pack_bf16(v.z, v.w));
        }
      }
    }
    __syncthreads();
  }
}

// fused1: blocks < GB run gemm layer-1; the rest run cscatter chunks.
__global__ __launch_bounds__(512) void fused1(
    const float* __restrict__ x, const unsigned* __restrict__ WtP0,
    const unsigned* __restrict__ WtS0, unsigned* __restrict__ Sb,
    unsigned* __restrict__ PH, const float* __restrict__ a_src0,
    const float* __restrict__ a_trg0, float* __restrict__ ssrc,
    float* __restrict__ strg, int M, int GB, const int* __restrict__ src,
    const int* __restrict__ trg, int* __restrict__ gcur,
    unsigned* __restrict__ EB, int E, int NC) {
  __shared__ __align__(16) char ldsraw[33792];
  if ((int)blockIdx.x < GB) {
    gemm_body<256, true>(ldsraw, blockIdx.x * 128, x, WtP0, WtS0, Sb, PH,
                         a_src0, a_trg0, ssrc, strg, M);
  } else {
    cscatter_body(ldsraw, blockIdx.x - GB, src, trg, gcur, EB, E, NC);
  }
}

__global__ __launch_bounds__(512) void gemm2(
    const void* __restrict__ Hb, const unsigned* __restrict__ WtP2,
    const unsigned* __restrict__ WtS2, unsigned* __restrict__ Sb,
    unsigned* __restrict__ PH, const float* __restrict__ a_src2,
    const float* __restrict__ a_trg2, float* __restrict__ ssrc,
    float* __restrict__ strg, int M) {
  __shared__ __align__(16) char ldsraw[33792];
  gemm_body<128, false>(ldsraw, blockIdx.x * 128, Hb, WtP2, WtS2, Sb, PH,
                        a_src2, a_trg2, ssrc, strg, M);
}

// ---------------------------------------------------------------------------
// Fused aggregation: head-split scores, 32-edge chunks, 16-deep gather
// pipeline, per-half denominator reduction.
// LAYER==1: out = packed-bf16 relu(agg+skip+b). LAYER==2: fp32 head-mean.
// ---------------------------------------------------------------------------
template <int LAYER>
__global__ __launch_bounds__(256) void aggregate(
    const int* __restrict__ rowbeg, const int* __restrict__ rowend,
    const int* __restrict__ SS, const float2* __restrict__ ssrc,
    const float2* __restrict__ strg, const unsigned* __restrict__ PH,
    const unsigned* __restrict__ Sb, const float* __restrict__ bias,
    void* __restrict__ Outv, int Nn) {
  int wid = (int)((blockIdx.x * blockDim.x + threadIdx.x) >> 6);
  int lane = threadIdx.x & 63;
  if (wid >= Nn) return;
  int n = wid;
  bool hi = lane >= 32;
  float2 st2 = strg[n];
  float stv = hi ? st2.y : st2.x;
  int beg = rowbeg[n];
  int end = rowend[n];
  float accx = 0.f, accy = 0.f, dsum = 0.f;

  for (int base = beg; base < end; base += 32) {
    int cnt = end - base;
    if (cnt > 32) cnt = 32;
    int ej = lane & 31;
    int idx = base + ej;
    bool valid = idx < end;
    int sv = valid ? SS[idx] : 0;
    float2 es = ssrc[sv];
    float z = (hi ? es.y : es.x) + stv;
    z = (z >= 0.f) ? z : NEG_SLOPE * z;
    float g = __expf(z);
    if (!valid) g = 0.f;
    {
      float gr = g;
#pragma unroll
      for (int m = 1; m < 32; m <<= 1) gr += __shfl_xor(gr, m, 64);
      dsum += gr;
    }
    int j = 0;
    for (; j + 16 <= cnt; j += 16) {
      unsigned wv[16];
      float gh[16];
#pragma unroll
      for (int k = 0; k < 16; ++k) {
        int s = __builtin_amdgcn_readlane(sv, j + k);
        wv[k] = PH[(size_t)s * 64 + lane];
      }
#pragma unroll
      for (int k = 0; k < 16; ++k) gh[k] = __shfl(g, j + k, 32);
#pragma unroll
      for (int k = 0; k < 16; ++k) {
        accx = fmaf(bflo(wv[k]), gh[k], accx);
        accy = fmaf(bfhi(wv[k]), gh[k], accy);
      }
    }
    for (; j + 8 <= cnt; j += 8) {
      unsigned wv[8];
      float gh[8];
#pragma unroll
      for (int k = 0; k < 8; ++k) {
        int s = __builtin_amdgcn_readlane(sv, j + k);
        wv[k] = PH[(size_t)s * 64 + lane];
      }
#pragma unroll
      for (int k = 0; k < 8; ++k) gh[k] = __shfl(g, j + k, 32);
#pragma unroll
      for (int k = 0; k < 8; ++k) {
        accx = fmaf(bflo(wv[k]), gh[k], accx);
        accy = fmaf(bfhi(wv[k]), gh[k], accy);
      }
    }
    for (; j < cnt; ++j) {
      int s = __builtin_amdgcn_readlane(sv, j);
      unsigned wv = PH[(size_t)s * 64 + lane];
      float gh = __shfl(g, j, 32);
      accx = fmaf(bflo(wv), gh, accx);
      accy = fmaf(bfhi(wv), gh, accy);
    }
  }

  float inv = 1.0f / (dsum + 1e-16f);
  accx *= inv;
  accy *= inv;
  unsigned skv = Sb[(size_t)n * 64 + lane];
  float skx = bflo(skv);
  float sky = bfhi(skv);
  if (LAYER == 1) {
    float2 b = *(const float2*)&bias[lane * 2];
    float zx = fmaxf(accx + skx + b.x, 0.f);
    float zy = fmaxf(accy + sky + b.y, 0.f);
    ((unsigned*)Outv)[(size_t)n * 64 + lane] = pack_bf16(zx, zy);
  } else {
    float zx = accx + skx;
    float zy = accy + sky;
    float ox = __shfl(zx, lane + 32, 64);
    float oy = __shfl(zy, lane + 32, 64);
    if (lane < 32) {
      float2 b = *(const float2*)&bias[lane * 2];
      float rx = 0.5f * (zx + ox) + b.x;
      float ry = 0.5f * (zy + oy) + b.y;
      *(float2*)&((float*)Outv)[(size_t)n * 64 + lane * 2] =
          make_float2(rx, ry);
    }
  }
}

// ---------------------------------------------------------------------------
extern "C" void kernel_launch(void* const* d_in, const int* in_sizes, int n_in,
                              void* d_out, int out_size, void* d_ws,
                              size_t ws_size, hipStream_t stream) {
  const float* x = (const float*)d_in[0];
  const int* ei = (const int*)d_in[1];
  const float* W0 = (const float*)d_in[2];
  const float* a_src0 = (const float*)d_in[3];
  const float* a_trg0 = (const float*)d_in[4];
  const float* Wsk0 = (const float*)d_in[5];
  const float* b0 = (const float*)d_in[6];
  const float* W2 = (const float*)d_in[7];
  const float* a_src2 = (const float*)d_in[8];
  const float* a_trg2 = (const float*)d_in[9];
  const float* Wsk2 = (const float*)d_in[10];
  const float* b2 = (const float*)d_in[11];

  const int FIN = 256;
  const int N = in_sizes[0] / FIN;
  const int E = in_sizes[1] / 2;
  const int* src = ei;
  const int* trg = ei + E;
  const int NC = (N + (1 << CBSH) - 1) >> CBSH;

  char* base = (char*)d_ws;
  size_t off = 0;
  auto alloc = [&](size_t bytes) -> void* {
    void* p = base + off;
    off += (bytes + 255) & ~(size_t)255;
    return p;
  };
  unsigned* PH = (unsigned*)alloc((size_t)N * 64 * sizeof(unsigned));
  unsigned* Sb = (unsigned*)alloc((size_t)N * 64 * sizeof(unsigned));
  unsigned* Hb = (unsigned*)alloc((size_t)N * 64 * sizeof(unsigned));
  int* SS = (int*)alloc((size_t)NC * BCAP * sizeof(int));
  unsigned* EB = (unsigned*)alloc((size_t)NC * BCAP * sizeof(unsigned));
  float* ssrc = (float*)alloc((size_t)N * 2 * sizeof(float));
  float* strg = (float*)alloc((size_t)N * 2 * sizeof(float));
  int* rowbeg = (int*)alloc((size_t)N * sizeof(int));
  int* rowend = (int*)alloc((size_t)N * sizeof(int));
  int* gcur = (int*)alloc((size_t)MAXNC * sizeof(int));
  unsigned* WtP0 = (unsigned*)alloc((size_t)128 * 256 * 2);
  unsigned* WtS0 = (unsigned*)alloc((size_t)128 * 256 * 2);
  unsigned* WtP2 = (unsigned*)alloc((size_t)128 * 128 * 2);
  unsigned* WtS2 = (unsigned*)alloc((size_t)128 * 128 * 2);

  dim3 blk(256);
  dim3 blk512(512);
  int gemmBlocks = (N + 127) / 128;
  int nodeBlocks = (N + 3) / 4;
  int chunkBlocks = (E + 4095) / 4096;
  int prepBlocks = (12288 + MAXNC + 255) / 256;

  // ---- prep: 4x weight transpose/convert + gcur zero (one launch) ----
  prep<<<prepBlocks, blk, 0, stream>>>(W0, Wsk0, W2, Wsk2, WtP0, WtS0, WtP2,
                                       WtS2, gcur);

  // ---- fused: gemm layer-1 || CSR cscatter ----
  fused1<<<gemmBlocks + chunkBlocks, blk512, 0, stream>>>(
      x, WtP0, WtS0, Sb, PH, a_src0, a_trg0, ssrc, strg, N, gemmBlocks, src,
      trg, gcur, EB, E, NC);
  bfill<<<NC, blk, 0, stream>>>(EB, gcur, rowbeg, rowend, SS, N);

  // ---- layer 1 aggregate ----
  aggregate<1><<<nodeBlocks, blk, 0, stream>>>(
      rowbeg, rowend, SS, (const float2*)ssrc, (const float2*)strg, PH, Sb, b0,
      Hb, N);
  // ---- layer 2 ----
  gemm2<<<gemmBlocks, blk512, 0, stream>>>(Hb, WtP2, WtS2, Sb, PH, a_src2,
                                           a_trg2, ssrc, strg, N);
  aggregate<2><<<nodeBlocks, blk, 0, stream>>>(
      rowbeg, rowend, SS, (const float2*)ssrc, (const float2*)strg, PH, Sb, b2,
      d_out, N);
}

// Round 19
// 143.463 us; speedup vs baseline: 1.0950x; 1.0950x over previous
//
#include <hip/hip_runtime.h>

#define NEG_SLOPE 0.2f
#define CBSH 7            // 128 nodes per coarse bucket
#define MAXNC 512         // max buckets (N <= 65536)
#define BCAP 4096         // fixed per-bucket edge capacity (mean ~2046)

typedef __attribute__((ext_vector_type(8))) short short8;
typedef __attribute__((ext_vector_type(4))) float f32x4;

__device__ __forceinline__ unsigned short f2bf(float f) {
  unsigned u = __float_as_uint(f);
  unsigned r = (u + 0x7FFFu + ((u >> 16) & 1u)) >> 16;
  return (unsigned short)r;
}
__device__ __forceinline__ unsigned pack_bf16(float lo, float hi) {
  return (unsigned)f2bf(lo) | ((unsigned)f2bf(hi) << 16);
}
__device__ __forceinline__ float bflo(unsigned u) {
  return __uint_as_float(u << 16);
}
__device__ __forceinline__ float bfhi(unsigned u) {
  return __uint_as_float(u & 0xFFFF0000u);
}
__device__ __forceinline__ void gload_lds16(const void* g, void* l) {
  __builtin_amdgcn_global_load_lds(
      (const __attribute__((address_space(1))) unsigned*)g,
      (__attribute__((address_space(3))) unsigned*)l, 16, 0, 0);
}

// ---------------------------------------------------------------------------
// prep: all four W[K][128] fp32 -> Wt[128][K] bf16 transposes + gcur zeroing
// in ONE launch. Segment boundaries are multiples of 64 (wave-clean).
// ---------------------------------------------------------------------------
__device__ __forceinline__ void wconv_item(const float* __restrict__ W,
                                           unsigned* __restrict__ Wt, int K,
                                           int t) {
  int per = K >> 3;
  int col = t / per;
  int kc = (t - col * per) << 3;
  float w[8];
#pragma unroll
  for (int j = 0; j < 8; ++j) w[j] = W[(size_t)(kc + j) * 128 + col];
  uint4 o = make_uint4(pack_bf16(w[0], w[1]), pack_bf16(w[2], w[3]),
                       pack_bf16(w[4], w[5]), pack_bf16(w[6], w[7]));
  *(uint4*)&Wt[((size_t)col * K + kc) >> 1] = o;
}

__global__ __launch_bounds__(256) void prep(
    const float* __restrict__ W0, const float* __restrict__ Ws0,
    const float* __restrict__ W2c, const float* __restrict__ Ws2,
    unsigned* __restrict__ WtP0, unsigned* __restrict__ WtS0,
    unsigned* __restrict__ WtP2, unsigned* __restrict__ WtS2,
    int* __restrict__ gcur) {
  int t = blockIdx.x * 256 + threadIdx.x;
  if (t < 4096) wconv_item(W0, WtP0, 256, t);
  else if (t < 8192) wconv_item(Ws0, WtS0, 256, t - 4096);
  else if (t < 10240) wconv_item(W2c, WtP2, 128, t - 8192);
  else if (t < 12288) wconv_item(Ws2, WtS2, 128, t - 10240);
  else if (t < 12288 + MAXNC) gcur[t - 12288] = 0;
}

// ---------------------------------------------------------------------------
// cscatter body (512 threads): block-local counting sort of a 4096-edge
// chunk; per-bucket runs burst-written into cb*BCAP + reserved global run.
// ---------------------------------------------------------------------------
__device__ void cscatter_body(char* ldsraw, int chunk,
                              const int* __restrict__ src,
                              const int* __restrict__ trg,
                              int* __restrict__ gcur,
                              unsigned* __restrict__ EB, int E, int NC) {
  int* hist = (int*)ldsraw;
  int* gb = hist + MAXNC;
  int* lcur = gb + MAXNC;
  unsigned* lbuf = (unsigned*)(lcur + MAXNC);
  unsigned short* cb16 = (unsigned short*)(lbuf + 4096);
  int tid = threadIdx.x;
  int e0 = chunk * 4096;
  int cnt = E - e0;
  if (cnt > 4096) cnt = 4096;
  for (int i = tid; i < NC; i += 512) hist[i] = 0;
  __syncthreads();
  unsigned pk[8];
  unsigned short cbr[8];
  int mine = 0;
#pragma unroll
  for (int j = 0; j < 8; ++j) {
    int i = tid + j * 512;
    if (i < cnt) {
      int e = e0 + i;
      int s = src[e];
      int t = trg[e];
      int cb = t >> CBSH;
      pk[j] = ((unsigned)s << CBSH) | (unsigned)(t & ((1 << CBSH) - 1));
      cbr[j] = (unsigned short)cb;
      atomicAdd(&hist[cb], 1);
      mine = j + 1;
    }
  }
  __syncthreads();
  for (int i = tid; i < NC; i += 512)
    gb[i] = hist[i] ? (i * BCAP + atomicAdd(&gcur[i], hist[i])) : 0;
  __syncthreads();
  if (tid == 0) {
    int run = 0;
    for (int i = 0; i < NC; ++i) {
      int v = hist[i];
      hist[i] = run;
      run += v;
    }
  }
  __syncthreads();
  for (int i = tid; i < NC; i += 512) lcur[i] = hist[i];
  __syncthreads();
  for (int j = 0; j < mine; ++j) {
    int p = atomicAdd(&lcur[cbr[j]], 1);
    lbuf[p] = pk[j];
    cb16[p] = cbr[j];
  }
  __syncthreads();
  for (int i = tid; i < cnt; i += 512) {
    int cb = cb16[i];
    EB[gb[cb] + (i - hist[cb])] = lbuf[i];
  }
}

// One block per bucket: per-node degrees -> rowbeg/rowend, in-bucket scatter.
// Prefix scan parallelized (Hillis-Steele over 128 entries, 7 steps).
__global__ __launch_bounds__(256) void bfill(const unsigned* __restrict__ EB,
                                             const int* __restrict__ gcur,
                                             int* __restrict__ rowbeg,
                                             int* __restrict__ rowend,
                                             int* __restrict__ SS, int N) {
  __shared__ int deg[128], pfx[128], cur[128];
  int cb = blockIdx.x;
  int b0 = cb * BCAP;
  int b1 = b0 + gcur[cb];
  int n0 = cb << CBSH;
  int tid = threadIdx.x;
  if (tid < 128) deg[tid] = 0;
  __syncthreads();
  for (int i = b0 + tid; i < b1; i += 256)
    atomicAdd(&deg[EB[i] & ((1 << CBSH) - 1)], 1);
  __syncthreads();
  if (tid < 128) pfx[tid] = deg[tid];
  __syncthreads();
#pragma unroll
  for (int s = 1; s < 128; s <<= 1) {
    int v = 0;
    if (tid < 128 && tid >= s) v = pfx[tid - s];
    __syncthreads();
    if (tid < 128) pfx[tid] += v;
    __syncthreads();
  }
  if (tid < 128) {
    int lo = b0 + pfx[tid] - deg[tid];
    cur[tid] = lo;
    int n = n0 + tid;
    if (n < N) {
      rowbeg[n] = lo;
      rowend[n] = lo + deg[tid];
    }
  }
  __syncthreads();
  for (int i = b0 + tid; i < b1; i += 256) {
    unsigned pk = EB[i];
    int pos = atomicAdd(&cur[pk & ((1 << CBSH) - 1)], 1);
    SS[pos] = (int)(pk >> CBSH);
  }
}

// ---------------------------------------------------------------------------
// gemm body — 128-row tile, 8 waves (512 thr), K_STEP=32 (verified passing).
// LDS: A-frags 8KB @0, BP @8192, BS @16384; epilogue Cs[64][132] aliases,
// two 64-row halves.
// ---------------------------------------------------------------------------
template <int KK, bool AF32>
__device__ void gemm_body(char* ldsraw, int row0, const void* __restrict__ Av,
                          const unsigned* __restrict__ BtP,
                          const unsigned* __restrict__ BtS,
                          unsigned* __restrict__ Cb,
                          unsigned* __restrict__ PH,
                          const float* __restrict__ a_src,
                          const float* __restrict__ a_trg,
                          float* __restrict__ ssrc, float* __restrict__ strg,
                          int M) {
  constexpr int NSTEP = KK / 32;
  float(*Cs)[132] = (float(*)[132])ldsraw;

  const int tid = threadIdx.x;
  const int lane = tid & 63;
  const int w = tid >> 6;  // 0..7

  f32x4 accP[8], accS[8];
#pragma unroll
  for (int c = 0; c < 8; ++c) {
    accP[c] = (f32x4)0.f;
    accS[c] = (f32x4)0.f;
  }

  const int arow = tid >> 2;
  const int akq = (tid & 3) << 3;
  const int agr = row0 + arow;
  const int abyte =
      ((((arow >> 4) << 6) | ((tid & 3) << 4) | (arow & 15)) << 4);
  const unsigned short* BP16 = (const unsigned short*)BtP;
  const unsigned short* BS16 = (const unsigned short*)BtS;
  const int bg = lane >> 4;
  const int br = lane & 15;

  for (int t = 0; t < NSTEP; ++t) {
    const int k0 = t << 5;
    {
      size_t eoff = (size_t)(16 * w + br) * KK + k0 + 8 * bg;
      gload_lds16(BP16 + eoff, ldsraw + 8192 + w * 1024);
      gload_lds16(BS16 + eoff, ldsraw + 16384 + w * 1024);
    }
    {
      uint4 p;
      if constexpr (AF32) {
        const float* A = (const float*)Av;
        float4 v0 = make_float4(0.f, 0.f, 0.f, 0.f), v1 = v0;
        if (agr < M) {
          v0 = *(const float4*)&A[(size_t)agr * KK + k0 + akq];
          v1 = *(const float4*)&A[(size_t)agr * KK + k0 + akq + 4];
        }
        p = make_uint4(pack_bf16(v0.x, v0.y), pack_bf16(v0.z, v0.w),
                       pack_bf16(v1.x, v1.y), pack_bf16(v1.z, v1.w));
      } else {
        const unsigned short* A = (const unsigned short*)Av;
        p = make_uint4(0u, 0u, 0u, 0u);
        if (agr < M) p = *(const uint4*)&A[(size_t)agr * KK + k0 + akq];
      }
      *(uint4*)(ldsraw + abyte) = p;
    }
    __syncthreads();
    short8 af = *(const short8*)(ldsraw + w * 1024 + lane * 16);
#pragma unroll
    for (int c = 0; c < 8; ++c) {
      short8 bp = *(const short8*)(ldsraw + 8192 + c * 1024 + lane * 16);
      accP[c] =
          __builtin_amdgcn_mfma_f32_16x16x32_bf16(af, bp, accP[c], 0, 0, 0);
      short8 bs = *(const short8*)(ldsraw + 16384 + c * 1024 + lane * 16);
      accS[c] =
          __builtin_amdgcn_mfma_f32_16x16x32_bf16(af, bs, accS[c], 0, 0, 0);
    }
    __syncthreads();
  }

  const int hrow = lane >> 5;
  const int c32 = lane & 31;
  const int wh = w >> 2;
  const int w4 = w & 3;

  // ---- proj epilogue (two 64-row halves): PH (bf16) + fused scores ----
#pragma unroll
  for (int h = 0; h < 2; ++h) {
    if (wh == h) {
#pragma unroll
      for (int c = 0; c < 8; ++c)
#pragma unroll
        for (int r = 0; r < 4; ++r)
          Cs[16 * w4 + ((lane >> 4) << 2) + r][16 * c + (lane & 15)] =
              accP[c][r];
    }
    __syncthreads();
    if (wh == h) {
#pragma unroll
      for (int i = 0; i < 8; ++i) {
        int lr = 16 * w4 + 2 * i + hrow;
        int gr = row0 + 64 * h + lr;
        if (gr < M) {
          float4 v = *(const float4*)&Cs[lr][c32 * 4];
          *(uint2*)&PH[(size_t)gr * 64 + c32 * 2] =
              make_uint2(pack_bf16(v.x, v.y), pack_bf16(v.z, v.w));
        }
      }
      int tid4 = tid - h * 256;
      int srow = tid4 >> 2;
      int q = tid4 & 3;
      int gr = row0 + 64 * h + srow;
      float ds = 0.f, dt = 0.f;
#pragma unroll
      for (int j = 0; j < 8; ++j) {
        int col = q * 32 + j * 4;
        float4 v = *(const float4*)&Cs[srow][col];
        float4 asv = *(const float4*)&a_src[col];
        float4 atv = *(const float4*)&a_trg[col];
        ds += v.x * asv.x + v.y * asv.y + v.z * asv.z + v.w * asv.w;
        dt += v.x * atv.x + v.y * atv.y + v.z * atv.z + v.w * atv.w;
      }
      ds += __shfl_xor(ds, 1, 64);
      dt += __shfl_xor(dt, 1, 64);
      if (gr < M && (q & 1) == 0) {
        int hh = q >> 1;
        ssrc[gr * 2 + hh] = ds;
        strg[gr * 2 + hh] = dt;
      }
    }
    __syncthreads();
  }

  // ---- skip epilogue (two halves): Cb (packed bf16) ----
#pragma unroll
  for (int h = 0; h < 2; ++h) {
    if (wh == h) {
#pragma unroll
      for (int c = 0; c < 8; ++c)
#pragma unroll
        for (int r = 0; r < 4; ++r)
          Cs[16 * w4 + ((lane >> 4) << 2) + r][16 * c + (lane & 15)] =
              accS[c][r];
    }
    __syncthreads();
    if (wh == h) {
#pragma unroll
      for (int i = 0; i < 8; ++i) {
        int lr = 16 * w4 + 2 * i + hrow;
        int gr = row0 + 64 * h + lr;
        if (gr < M) {
          float4 v = *(const float4*)&Cs[lr][c32 * 4];
          *(uint2*)&Cb[(size_t)gr * 64 + c32 * 2] =
              make_uint2(pack_bf16(v.x, v.y), pack_bf16(v.z, v.w));
        }
      }
    }
    __syncthreads();
  }
}

// fused1: blocks < GB run gemm layer-1; the rest run cscatter chunks.
__global__ __launch_bounds__(512) void fused1(
    const float* __restrict__ x, const unsigned* __restrict__ WtP0,
    const unsigned* __restrict__ WtS0, unsigned* __restrict__ Sb,
    unsigned* __restrict__ PH, const float* __restrict__ a_src0,
    const float* __restrict__ a_trg0, float* __restrict__ ssrc,
    float* __restrict__ strg, int M, int GB, const int* __restrict__ src,
    const int* __restrict__ trg, int* __restrict__ gcur,
    unsigned* __restrict__ EB, int E, int NC) {
  __shared__ __align__(16) char ldsraw[33792];
  if ((int)blockIdx.x < GB) {
    gemm_body<256, true>(ldsraw, blockIdx.x * 128, x, WtP0, WtS0, Sb, PH,
                         a_src0, a_trg0, ssrc, strg, M);
  } else {
    cscatter_body(ldsraw, blockIdx.x - GB, src, trg, gcur, EB, E, NC);
  }
}

__global__ __launch_bounds__(512) void gemm2(
    const void* __restrict__ Hb, const unsigned* __restrict__ WtP2,
    const unsigned* __restrict__ WtS2, unsigned* __restrict__ Sb,
    unsigned* __restrict__ PH, const float* __restrict__ a_src2,
    const float* __restrict__ a_trg2, float* __restrict__ ssrc,
    float* __restrict__ strg, int M) {
  __shared__ __align__(16) char ldsraw[33792];
  gemm_body<128, false>(ldsraw, blockIdx.x * 128, Hb, WtP2, WtS2, Sb, PH,
                        a_src2, a_trg2, ssrc, strg, M);
}

// ---------------------------------------------------------------------------
// Fused aggregation (round-17 verified config: 8-deep pipeline, VGPR~32,
// 63% occupancy — the fabric-bound floor): head-split scores, 32-edge
// chunks, per-half denominator reduction.
// LAYER==1: out = packed-bf16 relu(agg+skip+b). LAYER==2: fp32 head-mean.
// ---------------------------------------------------------------------------
template <int LAYER>
__global__ __launch_bounds__(256) void aggregate(
    const int* __restrict__ rowbeg, const int* __restrict__ rowend,
    const int* __restrict__ SS, const float2* __restrict__ ssrc,
    const float2* __restrict__ strg, const unsigned* __restrict__ PH,
    const unsigned* __restrict__ Sb, const float* __restrict__ bias,
    void* __restrict__ Outv, int Nn) {
  int wid = (int)((blockIdx.x * blockDim.x + threadIdx.x) >> 6);
  int lane = threadIdx.x & 63;
  if (wid >= Nn) return;
  int n = wid;
  bool hi = lane >= 32;
  float2 st2 = strg[n];
  float stv = hi ? st2.y : st2.x;
  int beg = rowbeg[n];
  int end = rowend[n];
  float accx = 0.f, accy = 0.f, dsum = 0.f;

  for (int base = beg; base < end; base += 32) {
    int cnt = end - base;
    if (cnt > 32) cnt = 32;
    int ej = lane & 31;
    int idx = base + ej;
    bool valid = idx < end;
    int sv = valid ? SS[idx] : 0;
    float2 es = ssrc[sv];
    float z = (hi ? es.y : es.x) + stv;
    z = (z >= 0.f) ? z : NEG_SLOPE * z;
    float g = __expf(z);
    if (!valid) g = 0.f;
    {
      float gr = g;
#pragma unroll
      for (int m = 1; m < 32; m <<= 1) gr += __shfl_xor(gr, m, 64);
      dsum += gr;
    }
    int j = 0;
    for (; j + 8 <= cnt; j += 8) {
      unsigned wv[8];
      float gh[8];
#pragma unroll
      for (int k = 0; k < 8; ++k) {
        int s = __builtin_amdgcn_readlane(sv, j + k);
        wv[k] = PH[(size_t)s * 64 + lane];
      }
#pragma unroll
      for (int k = 0; k < 8; ++k) gh[k] = __shfl(g, j + k, 32);
#pragma unroll
      for (int k = 0; k < 8; ++k) {
        accx = fmaf(bflo(wv[k]), gh[k], accx);
        accy = fmaf(bfhi(wv[k]), gh[k], accy);
      }
    }
    for (; j < cnt; ++j) {
      int s = __builtin_amdgcn_readlane(sv, j);
      unsigned wv = PH[(size_t)s * 64 + lane];
      float gh = __shfl(g, j, 32);
      accx = fmaf(bflo(wv), gh, accx);
      accy = fmaf(bfhi(wv), gh, accy);
    }
  }

  float inv = 1.0f / (dsum + 1e-16f);
  accx *= inv;
  accy *= inv;
  unsigned skv = Sb[(size_t)n * 64 + lane];
  float skx = bflo(skv);
  float sky = bfhi(skv);
  if (LAYER == 1) {
    float2 b = *(const float2*)&bias[lane * 2];
    float zx = fmaxf(accx + skx + b.x, 0.f);
    float zy = fmaxf(accy + sky + b.y, 0.f);
    ((unsigned*)Outv)[(size_t)n * 64 + lane] = pack_bf16(zx, zy);
  } else {
    float zx = accx + skx;
    float zy = accy + sky;
    float ox = __shfl(zx, lane + 32, 64);
    float oy = __shfl(zy, lane + 32, 64);
    if (lane < 32) {
      float2 b = *(const float2*)&bias[lane * 2];
      float rx = 0.5f * (zx + ox) + b.x;
      float ry = 0.5f * (zy + oy) + b.y;
      *(float2*)&((float*)Outv)[(size_t)n * 64 + lane * 2] =
          make_float2(rx, ry);
    }
  }
}

// ---------------------------------------------------------------------------
extern "C" void kernel_launch(void* const* d_in, const int* in_sizes, int n_in,
                              void* d_out, int out_size, void* d_ws,
                              size_t ws_size, hipStream_t stream) {
  const float* x = (const float*)d_in[0];
  const int* ei = (const int*)d_in[1];
  const float* W0 = (const float*)d_in[2];
  const float* a_src0 = (const float*)d_in[3];
  const float* a_trg0 = (const float*)d_in[4];
  const float* Wsk0 = (const float*)d_in[5];
  const float* b0 = (const float*)d_in[6];
  const float* W2 = (const float*)d_in[7];
  const float* a_src2 = (const float*)d_in[8];
  const float* a_trg2 = (const float*)d_in[9];
  const float* Wsk2 = (const float*)d_in[10];
  const float* b2 = (const float*)d_in[11];

  const int FIN = 256;
  const int N = in_sizes[0] / FIN;
  const int E = in_sizes[1] / 2;
  const int* src = ei;
  const int* trg = ei + E;
  const int NC = (N + (1 << CBSH) - 1) >> CBSH;

  char* base = (char*)d_ws;
  size_t off = 0;
  auto alloc = [&](size_t bytes) -> void* {
    void* p = base + off;
    off += (bytes + 255) & ~(size_t)255;
    return p;
  };
  unsigned* PH = (unsigned*)alloc((size_t)N * 64 * sizeof(unsigned));
  unsigned* Sb = (unsigned*)alloc((size_t)N * 64 * sizeof(unsigned));
  unsigned* Hb = (unsigned*)alloc((size_t)N * 64 * sizeof(unsigned));
  int* SS = (int*)alloc((size_t)NC * BCAP * sizeof(int));
  unsigned* EB = (unsigned*)alloc((size_t)NC * BCAP * sizeof(unsigned));
  float* ssrc = (float*)alloc((size_t)N * 2 * sizeof(float));
  float* strg = (float*)alloc((size_t)N * 2 * sizeof(float));
  int* rowbeg = (int*)alloc((size_t)N * sizeof(int));
  int* rowend = (int*)alloc((size_t)N * sizeof(int));
  int* gcur = (int*)alloc((size_t)MAXNC * sizeof(int));
  unsigned* WtP0 = (unsigned*)alloc((size_t)128 * 256 * 2);
  unsigned* WtS0 = (unsigned*)alloc((size_t)128 * 256 * 2);
  unsigned* WtP2 = (unsigned*)alloc((size_t)128 * 128 * 2);
  unsigned* WtS2 = (unsigned*)alloc((size_t)128 * 128 * 2);

  dim3 blk(256);
  dim3 blk512(512);
  int gemmBlocks = (N + 127) / 128;
  int nodeBlocks = (N + 3) / 4;
  int chunkBlocks = (E + 4095) / 4096;
  int prepBlocks = (12288 + MAXNC + 255) / 256;

  // ---- prep: 4x weight transpose/convert + gcur zero (one launch) ----
  prep<<<prepBlocks, blk, 0, stream>>>(W0, Wsk0, W2, Wsk2, WtP0, WtS0, WtP2,
                                       WtS2, gcur);

  // ---- fused: gemm layer-1 || CSR cscatter ----
  fused1<<<gemmBlocks + chunkBlocks, blk512, 0, stream>>>(
      x, WtP0, WtS0, Sb, PH, a_src0, a_trg0, ssrc, strg, N, gemmBlocks, src,
      trg, gcur, EB, E, NC);
  bfill<<<NC, blk, 0, stream>>>(EB, gcur, rowbeg, rowend, SS, N);

  // ---- layer 1 aggregate ----
  aggregate<1><<<nodeBlocks, blk, 0, stream>>>(
      rowbeg, rowend, SS, (const float2*)ssrc, (const float2*)strg, PH, Sb, b0,
      Hb, N);
  // ---- layer 2 ----
  gemm2<<<gemmBlocks, blk512, 0, stream>>>(Hb, WtP2, WtS2, Sb, PH, a_src2,
                                           a_trg2, ssrc, strg, N);
  aggregate<2><<<nodeBlocks, blk, 0, stream>>>(
      rowbeg, rowend, SS, (const float2*)ssrc, (const float2*)strg, PH, Sb, b2,
      d_out, N);
}